// Round 4
// baseline (265.980 us; speedup 1.0000x reference)
//
#include <hip/hip_runtime.h>

#define NB   4
#define CH   256
#define CQK  32
#define NPOS 4096
#define KT   64
#define NCHK (NPOS / KT)
#define QT   64

typedef __attribute__((ext_vector_type(8))) short bf16x8;
typedef __attribute__((ext_vector_type(4))) float f32x4;
typedef unsigned short u16;
typedef unsigned int   u32;

static __device__ __forceinline__ u16 f2bf(float x) {
    union { float f; u32 u; } c; c.f = x;
    u32 u = c.u + 0x7FFFu + ((c.u >> 16) & 1u);
    return (u16)(u >> 16);
}
static __device__ __forceinline__ u32 pack2(float a, float b) {
    return (u32)f2bf(a) | ((u32)f2bf(b) << 16);
}

// ---------------------------------------------------------------------------
// W concat + bf16 convert: wb[320][256] bf16 (rows: 32 q | 32 k | 256 v),
// bb[320] f32.  grid 80 x 256.
// ---------------------------------------------------------------------------
__global__ __launch_bounds__(256) void wcvt_kernel(
    const float* __restrict__ wq, const float* __restrict__ bq,
    const float* __restrict__ wk, const float* __restrict__ bk,
    const float* __restrict__ wv, const float* __restrict__ bv,
    u16* __restrict__ wb, float* __restrict__ bb)
{
    int idx = blockIdx.x * 256 + threadIdx.x;
    int e0 = idx * 4;
    const float* src; int off;
    if (e0 < 32 * 256)      { src = wq; off = e0; }
    else if (e0 < 64 * 256) { src = wk; off = e0 - 32 * 256; }
    else                    { src = wv; off = e0 - 64 * 256; }
    float4 v4 = *(const float4*)(src + off);
    *(uint2*)(wb + e0) = make_uint2(pack2(v4.x, v4.y), pack2(v4.z, v4.w));
    if (idx < 320) {
        float b = idx < 32 ? bq[idx] : (idx < 64 ? bk[idx - 32] : bv[idx - 64]);
        bb[idx] = b;
    }
}

// ---------------------------------------------------------------------------
// MFMA QKV projection.  grid = NB * (NPOS/32) = 512 blocks, 256 threads.
// 32-position tiles: x^T staged bf16 into XOR-swizzled LDS; B-frags in regs;
// A (W bf16) streamed from L2 with ping-pong prefetch; 80 mfma/wave.
// Outputs: q,k [B][N][32] bf16;  v [B][256][N] bf16.
// ---------------------------------------------------------------------------
__global__ __launch_bounds__(256, 1) void qkv_proj_kernel(
    const float* __restrict__ x, const u16* __restrict__ wb, const float* __restrict__ bb,
    u16* __restrict__ qo, u16* __restrict__ ko, u16* __restrict__ vo)
{
    __shared__ u16 ldsx[32][264];   // 32 rows x 528 B (16.9 KB)
    const int t  = threadIdx.x;
    const int b  = blockIdx.x >> 7;
    const int n0 = (blockIdx.x & 127) * 32;        // <= 4064: in bounds
    const float* xb = x + (size_t)b * CH * NPOS;

    // stage x^T fp32->bf16 (channel pairs packed into u32)
    #pragma unroll
    for (int it = 0; it < 4; ++it) {
        int idx = it * 256 + t;
        int cp = idx >> 3;          // 0..127
        int n4 = (idx & 7) * 4;     // 0..28
        int c  = cp * 2;
        float4 a = *(const float4*)(xb + (size_t)c * NPOS + n0 + n4);
        float4 d = *(const float4*)(xb + (size_t)(c + 1) * NPOS + n0 + n4);
        #pragma unroll
        for (int i = 0; i < 4; ++i) {
            int n = n4 + i;
            u32 pv = pack2(((const float*)&a)[i], ((const float*)&d)[i]);
            *(u32*)((char*)ldsx + n * 528 + ((c * 2) ^ ((n & 7) << 4))) = pv;
        }
    }
    __syncthreads();

    const int w = t >> 6, lane = t & 63, g8 = lane >> 4, l16 = lane & 15;

    bf16x8 bf[2][8];
    #pragma unroll
    for (int ns = 0; ns < 2; ++ns) {
        int n = ns * 16 + l16;
        const char* rowp = (const char*)ldsx + n * 528;
        int swz = (n & 7) << 4;
        #pragma unroll
        for (int ks = 0; ks < 8; ++ks)
            bf[ns][ks] = *(const bf16x8*)(rowp + ((ks * 64 + g8 * 16) ^ swz));
    }

    u16* qdst = qo + (size_t)b * NPOS * CQK;
    u16* kdst = ko + (size_t)b * NPOS * CQK;
    u16* vdst = vo + (size_t)b * CH * NPOS;

    bf16x8 afA[8], afB[8];
    #pragma unroll
    for (int ks = 0; ks < 8; ++ks)
        afA[ks] = *(const bf16x8*)(wb + (w * 5 * 16 + l16) * 256 + ks * 32 + g8 * 8);

    #pragma unroll
    for (int j = 0; j < 5; ++j) {
        int ot = w * 5 + j;
        bf16x8* afc = (j & 1) ? afB : afA;
        bf16x8* afn = (j & 1) ? afA : afB;
        if (j + 1 < 5) {
            int otn = ot + 1;
            #pragma unroll
            for (int ks = 0; ks < 8; ++ks)
                afn[ks] = *(const bf16x8*)(wb + (otn * 16 + l16) * 256 + ks * 32 + g8 * 8);
        }
        f32x4 acc[2];
        acc[0] = (f32x4){0.f, 0.f, 0.f, 0.f};
        acc[1] = (f32x4){0.f, 0.f, 0.f, 0.f};
        #pragma unroll
        for (int ks = 0; ks < 8; ++ks) {
            acc[0] = __builtin_amdgcn_mfma_f32_16x16x32_bf16(afc[ks], bf[0][ks], acc[0], 0, 0, 0);
            acc[1] = __builtin_amdgcn_mfma_f32_16x16x32_bf16(afc[ks], bf[1][ks], acc[1], 0, 0, 0);
        }
        float4 bias = *(const float4*)(bb + ot * 16 + g8 * 4);

        if (ot < 4) {          // q (ot 0,1) / k (ot 2,3): [n][32]
            u16* dst = (ot < 2 ? qdst : kdst);
            int ob = (ot & 1) * 16 + g8 * 4;
            #pragma unroll
            for (int ns = 0; ns < 2; ++ns) {
                int n = n0 + ns * 16 + l16;
                u32 lo = pack2(acc[ns][0] + bias.x, acc[ns][1] + bias.y);
                u32 hi = pack2(acc[ns][2] + bias.z, acc[ns][3] + bias.w);
                *(uint2*)(dst + (size_t)n * CQK + ob) = make_uint2(lo, hi);
            }
        } else {               // v: [ch][n]
            int orow = (ot - 4) * 16 + g8 * 4;
            const float* bp = (const float*)&bias;
            #pragma unroll
            for (int r = 0; r < 4; ++r)
                #pragma unroll
                for (int ns = 0; ns < 2; ++ns)
                    vdst[(size_t)(orow + r) * NPOS + n0 + ns * 16 + l16] =
                        f2bf(acc[ns][r] + bp[r]);
        }
    }
}

// ---------------------------------------------------------------------------
// Symmetric 8-wave flash attention.  grid 256 (1 block/CU), 512 threads.
// Wave w: strip (w&3) of 16 queries x channel-half (w>>2)*128.
// Waves 0-3 additionally produce: swapped QK^T (keys lane-local -> 2-shfl
// softmax reduce), defer-rescale online softmax, P -> XOR-swizzled dbuf LDS.
// All waves: PV 16 mfma/chunk from 2 ds_read_b128 A-frags + 16 reg V-frags
// loaded at top of chunk (latency hidden under softmax+barrier).
// One uniform __syncthreads per chunk; P/SC double-buffered.
// ---------------------------------------------------------------------------
#define P_OFF   0        // 2 bufs x 4 strips x 16 q x 128B = 16384
#define SC_OFF  16384    // 2 x 64 f32 = 512
#define LL_OFF  16896    // 64 f32 = 256
#define EP_OFF  17152    // 8 waves x 16ch x 20 f32 = 10240
#define SMEMSZ  27392

__global__ __launch_bounds__(512, 1) void attn_kernel(
    const u16* __restrict__ q, const u16* __restrict__ k, const u16* __restrict__ v,
    const float* __restrict__ input, const float* __restrict__ gamma,
    float* __restrict__ out)
{
    __shared__ __align__(16) char smem[SMEMSZ];
    const int t = threadIdx.x;
    const int w = t >> 6;
    const int lane = t & 63;
    const int g8 = lane >> 4;
    const int l16 = lane & 15;

    const int bid = blockIdx.x;
    const int b = (bid >> 1) & 3;
    const int tile = ((bid >> 3) << 1) | (bid & 1);
    const int i0 = tile * QT;

    const int strip = w & 3;
    const int ch0 = (w >> 2) * 128;
    const bool prod = (w < 4);

    const u16* kb = k + (size_t)b * NPOS * CQK;
    const u16* vb = v + (size_t)b * CH * NPOS;

    bf16x8 qf = {0,0,0,0,0,0,0,0};
    bf16x8 kA[4], kB[4];
    if (prod) {
        const u16* qb = q + (size_t)b * NPOS * CQK;
        qf = *(const bf16x8*)(qb + (size_t)(i0 + strip * 16 + l16) * CQK + g8 * 8);
        #pragma unroll
        for (int nt = 0; nt < 4; ++nt)
            kA[nt] = *(const bf16x8*)(kb + (size_t)(nt * 16 + l16) * CQK + g8 * 8);
    }

    f32x4 acc[8];
    #pragma unroll
    for (int ct = 0; ct < 8; ++ct) acc[ct] = (f32x4){0.f, 0.f, 0.f, 0.f};
    float mrun = -__builtin_inff(), lrun = 0.f;

    auto body = [&](int jc, bf16x8 (&kcur)[4], bf16x8 (&knxt)[4]) {
        const int buf = jc & 1;
        const int j0 = jc * KT;

        // V frags for THIS chunk (latency covered by softmax + barrier)
        bf16x8 vc[16];
        #pragma unroll
        for (int ct = 0; ct < 8; ++ct)
            #pragma unroll
            for (int ks = 0; ks < 2; ++ks)
                vc[ct * 2 + ks] = *(const bf16x8*)(vb + (size_t)(ch0 + ct * 16 + l16) * NPOS
                                                   + j0 + ks * 32 + g8 * 8);

        if (prod) {
            f32x4 z = {0.f, 0.f, 0.f, 0.f};
            f32x4 s[4];
            #pragma unroll
            for (int nt = 0; nt < 4; ++nt)   // S[key nt*16+g8*4+r][query l16]
                s[nt] = __builtin_amdgcn_mfma_f32_16x16x32_bf16(kcur[nt], qf, z, 0, 0, 0);
            if (jc + 1 < NCHK) {
                int j0n = j0 + KT;
                #pragma unroll
                for (int nt = 0; nt < 4; ++nt)
                    knxt[nt] = *(const bf16x8*)(kb + (size_t)(j0n + nt * 16 + l16) * CQK + g8 * 8);
            }
            // softmax: lane holds 16 keys of query l16; reduce across g8 (2 shfl)
            float mx = s[0][0];
            #pragma unroll
            for (int nt = 0; nt < 4; ++nt)
                #pragma unroll
                for (int r = 0; r < 4; ++r) mx = fmaxf(mx, s[nt][r]);
            mx = fmaxf(mx, __shfl_xor(mx, 16));
            mx = fmaxf(mx, __shfl_xor(mx, 32));
            bool need = mx > mrun + 8.0f;    // defer-rescale THR=8
            float sc = need ? __expf(mrun - mx) : 1.0f;   // exp(-inf)=0 first time
            if (need) mrun = mx;
            float p[4][4]; float ls = 0.f;
            #pragma unroll
            for (int nt = 0; nt < 4; ++nt)
                #pragma unroll
                for (int r = 0; r < 4; ++r) {
                    p[nt][r] = __expf(s[nt][r] - mrun);
                    ls += p[nt][r];
                }
            ls += __shfl_xor(ls, 16);
            ls += __shfl_xor(ls, 32);
            lrun = lrun * sc + ls;
            // P[query l16][key] bf16, XOR-swizzled 128B rows
            char* pb = smem + P_OFF + buf * 8192 + strip * 2048 + l16 * 128;
            int swz = (l16 & 7) << 4;
            #pragma unroll
            for (int nt = 0; nt < 4; ++nt)
                *(uint2*)(pb + ((nt * 32 + g8 * 8) ^ swz)) =
                    make_uint2(pack2(p[nt][0], p[nt][1]), pack2(p[nt][2], p[nt][3]));
            if (g8 == 0)
                *(float*)(smem + SC_OFF + buf * 256 + (strip * 16 + l16) * 4) = sc;
        }

        __syncthreads();

        // rescale (sc==1.0 normally -> exact no-op)
        f32x4 sc4 = *(const f32x4*)(smem + SC_OFF + buf * 256 + (strip * 16 + g8 * 4) * 4);
        #pragma unroll
        for (int ct = 0; ct < 8; ++ct) acc[ct] *= sc4;

        // PV: A-frags of this wave's strip, reused across 8 channel tiles
        const char* pb2 = smem + P_OFF + buf * 8192 + strip * 2048 + l16 * 128;
        int swz2 = (l16 & 7) << 4;
        bf16x8 pa0 = *(const bf16x8*)(pb2 + ((g8 * 16) ^ swz2));
        bf16x8 pa1 = *(const bf16x8*)(pb2 + ((64 + g8 * 16) ^ swz2));
        __builtin_amdgcn_s_setprio(1);
        #pragma unroll
        for (int ct = 0; ct < 8; ++ct) {
            acc[ct] = __builtin_amdgcn_mfma_f32_16x16x32_bf16(pa0, vc[ct * 2 + 0], acc[ct], 0, 0, 0);
            acc[ct] = __builtin_amdgcn_mfma_f32_16x16x32_bf16(pa1, vc[ct * 2 + 1], acc[ct], 0, 0, 0);
        }
        __builtin_amdgcn_s_setprio(0);
    };

    for (int jc = 0; jc < NCHK; jc += 2) {
        body(jc, kA, kB);
        body(jc + 1, kB, kA);
    }

    if (prod && g8 == 0)
        *(float*)(smem + LL_OFF + (strip * 16 + l16) * 4) = lrun;
    __syncthreads();

    f32x4 lv = *(const f32x4*)(smem + LL_OFF + (strip * 16 + g8 * 4) * 4);
    f32x4 one = {1.f, 1.f, 1.f, 1.f};
    f32x4 linv = one / lv;

    const float gmm = gamma[0];
    const float* inb = input + (size_t)b * CH * NPOS;
    float* ob = out + (size_t)b * CH * NPOS;
    char* ep = smem + EP_OFF + w * 1280;   // [16ch][20 f32]

    #pragma unroll
    for (int ct = 0; ct < 8; ++ct) {
        f32x4 val = acc[ct] * linv;
        #pragma unroll
        for (int r = 0; r < 4; ++r)
            *(float*)(ep + l16 * 80 + (g8 * 4 + r) * 4) = val[r];
        asm volatile("s_waitcnt lgkmcnt(0)" ::: "memory");
        f32x4 o4 = *(const f32x4*)(ep + l16 * 80 + g8 * 16);
        int ch = ch0 + ct * 16 + l16;
        size_t gi = (size_t)ch * NPOS + i0 + strip * 16 + g8 * 4;
        float4 in4 = *(const float4*)(inb + gi);
        float4 r4;
        r4.x = gmm * o4[0] + in4.x;
        r4.y = gmm * o4[1] + in4.y;
        r4.z = gmm * o4[2] + in4.z;
        r4.w = gmm * o4[3] + in4.w;
        *(float4*)(ob + gi) = r4;
        asm volatile("s_waitcnt lgkmcnt(0)" ::: "memory");
    }
}

// ---------------------------------------------------------------------------
extern "C" void kernel_launch(void* const* d_in, const int* in_sizes, int n_in,
                              void* d_out, int out_size, void* d_ws, size_t ws_size,
                              hipStream_t stream) {
    const float* input = (const float*)d_in[0];
    const float* wq    = (const float*)d_in[1];
    const float* bq    = (const float*)d_in[2];
    const float* wk    = (const float*)d_in[3];
    const float* bk    = (const float*)d_in[4];
    const float* wv    = (const float*)d_in[5];
    const float* bv    = (const float*)d_in[6];
    const float* gamma = (const float*)d_in[7];
    float* out = (float*)d_out;

    const size_t qk_elems = (size_t)NB * NPOS * CQK;   // 524288
    const size_t v_elems  = (size_t)NB * CH * NPOS;    // 4194304
    const size_t w_elems  = 320 * 256;                 // 81920
    size_t need = (2 * qk_elems + v_elems + w_elems) * sizeof(u16) + 320 * sizeof(float);
    if (ws_size < need) return;

    u16* qw = (u16*)d_ws;
    u16* kw = qw + qk_elems;
    u16* vw = kw + qk_elems;
    u16* wb = vw + v_elems;
    float* bbuf = (float*)(wb + w_elems);

    wcvt_kernel<<<dim3(80), dim3(256), 0, stream>>>(wq, bq, wk, bk, wv, bv, wb, bbuf);
    qkv_proj_kernel<<<dim3(NB * (NPOS / 32)), dim3(256), 0, stream>>>(input, wb, bbuf, qw, kw, vw);
    attn_kernel<<<dim3(NB * (NPOS / QT)), dim3(512), 0, stream>>>(qw, kw, vw, input, gamma, out);
}

// Round 5
// 116.949 us; speedup vs baseline: 2.2743x; 2.2743x over previous
//
#include <hip/hip_runtime.h>

#define NB   4
#define CH   256
#define CQK  32
#define NPOS 4096
#define KT   64
#define NCHK (NPOS / KT)
#define QT   64

typedef __attribute__((ext_vector_type(8))) short bf16x8;
typedef __attribute__((ext_vector_type(4))) float f32x4;
typedef unsigned short u16;
typedef unsigned int   u32;

static __device__ __forceinline__ u16 f2bf(float x) {
    union { float f; u32 u; } c; c.f = x;
    u32 u = c.u + 0x7FFFu + ((c.u >> 16) & 1u);
    return (u16)(u >> 16);
}
static __device__ __forceinline__ u32 pack2(float a, float b) {
    return (u32)f2bf(a) | ((u32)f2bf(b) << 16);
}

// ---------------------------------------------------------------------------
// W concat + bf16 convert: wb[320][256] bf16 (rows: 32 q | 32 k | 256 v),
// bb[320] f32.  grid 80 x 256.
// ---------------------------------------------------------------------------
__global__ __launch_bounds__(256) void wcvt_kernel(
    const float* __restrict__ wq, const float* __restrict__ bq,
    const float* __restrict__ wk, const float* __restrict__ bk,
    const float* __restrict__ wv, const float* __restrict__ bv,
    u16* __restrict__ wb, float* __restrict__ bb)
{
    int idx = blockIdx.x * 256 + threadIdx.x;
    int e0 = idx * 4;
    const float* src; int off;
    if (e0 < 32 * 256)      { src = wq; off = e0; }
    else if (e0 < 64 * 256) { src = wk; off = e0 - 32 * 256; }
    else                    { src = wv; off = e0 - 64 * 256; }
    float4 v4 = *(const float4*)(src + off);
    *(uint2*)(wb + e0) = make_uint2(pack2(v4.x, v4.y), pack2(v4.z, v4.w));
    if (idx < 320) {
        float b = idx < 32 ? bq[idx] : (idx < 64 ? bk[idx - 32] : bv[idx - 64]);
        bb[idx] = b;
    }
}

// ---------------------------------------------------------------------------
// MFMA QKV projection.  grid = NB * (NPOS/32) = 512 blocks, 256 threads.
// (unchanged from R4 — passed, ~13 us incl. wcvt)
// ---------------------------------------------------------------------------
__global__ __launch_bounds__(256, 1) void qkv_proj_kernel(
    const float* __restrict__ x, const u16* __restrict__ wb, const float* __restrict__ bb,
    u16* __restrict__ qo, u16* __restrict__ ko, u16* __restrict__ vo)
{
    __shared__ u16 ldsx[32][264];
    const int t  = threadIdx.x;
    const int b  = blockIdx.x >> 7;
    const int n0 = (blockIdx.x & 127) * 32;
    const float* xb = x + (size_t)b * CH * NPOS;

    #pragma unroll
    for (int it = 0; it < 4; ++it) {
        int idx = it * 256 + t;
        int cp = idx >> 3;
        int n4 = (idx & 7) * 4;
        int c  = cp * 2;
        float4 a = *(const float4*)(xb + (size_t)c * NPOS + n0 + n4);
        float4 d = *(const float4*)(xb + (size_t)(c + 1) * NPOS + n0 + n4);
        #pragma unroll
        for (int i = 0; i < 4; ++i) {
            int n = n4 + i;
            u32 pv = pack2(((const float*)&a)[i], ((const float*)&d)[i]);
            *(u32*)((char*)ldsx + n * 528 + ((c * 2) ^ ((n & 7) << 4))) = pv;
        }
    }
    __syncthreads();

    const int w = t >> 6, lane = t & 63, g8 = lane >> 4, l16 = lane & 15;

    bf16x8 bf[2][8];
    #pragma unroll
    for (int ns = 0; ns < 2; ++ns) {
        int n = ns * 16 + l16;
        const char* rowp = (const char*)ldsx + n * 528;
        int swz = (n & 7) << 4;
        #pragma unroll
        for (int ks = 0; ks < 8; ++ks)
            bf[ns][ks] = *(const bf16x8*)(rowp + ((ks * 64 + g8 * 16) ^ swz));
    }

    u16* qdst = qo + (size_t)b * NPOS * CQK;
    u16* kdst = ko + (size_t)b * NPOS * CQK;
    u16* vdst = vo + (size_t)b * CH * NPOS;

    bf16x8 afA[8], afB[8];
    #pragma unroll
    for (int ks = 0; ks < 8; ++ks)
        afA[ks] = *(const bf16x8*)(wb + (w * 5 * 16 + l16) * 256 + ks * 32 + g8 * 8);

    #pragma unroll
    for (int j = 0; j < 5; ++j) {
        int ot = w * 5 + j;
        bf16x8* afc = (j & 1) ? afB : afA;
        bf16x8* afn = (j & 1) ? afA : afB;
        if (j + 1 < 5) {
            int otn = ot + 1;
            #pragma unroll
            for (int ks = 0; ks < 8; ++ks)
                afn[ks] = *(const bf16x8*)(wb + (otn * 16 + l16) * 256 + ks * 32 + g8 * 8);
        }
        f32x4 acc[2];
        acc[0] = (f32x4){0.f, 0.f, 0.f, 0.f};
        acc[1] = (f32x4){0.f, 0.f, 0.f, 0.f};
        #pragma unroll
        for (int ks = 0; ks < 8; ++ks) {
            acc[0] = __builtin_amdgcn_mfma_f32_16x16x32_bf16(afc[ks], bf[0][ks], acc[0], 0, 0, 0);
            acc[1] = __builtin_amdgcn_mfma_f32_16x16x32_bf16(afc[ks], bf[1][ks], acc[1], 0, 0, 0);
        }
        float4 bias = *(const float4*)(bb + ot * 16 + g8 * 4);

        if (ot < 4) {
            u16* dst = (ot < 2 ? qdst : kdst);
            int ob = (ot & 1) * 16 + g8 * 4;
            #pragma unroll
            for (int ns = 0; ns < 2; ++ns) {
                int n = n0 + ns * 16 + l16;
                u32 lo = pack2(acc[ns][0] + bias.x, acc[ns][1] + bias.y);
                u32 hi = pack2(acc[ns][2] + bias.z, acc[ns][3] + bias.w);
                *(uint2*)(dst + (size_t)n * CQK + ob) = make_uint2(lo, hi);
            }
        } else {
            int orow = (ot - 4) * 16 + g8 * 4;
            const float* bp = (const float*)&bias;
            #pragma unroll
            for (int r = 0; r < 4; ++r)
                #pragma unroll
                for (int ns = 0; ns < 2; ++ns)
                    vdst[(size_t)(orow + r) * NPOS + n0 + ns * 16 + l16] =
                        f2bf(acc[ns][r] + bp[r]);
        }
    }
}

// ---------------------------------------------------------------------------
// Producer/consumer flash attention.  grid 256, 512 threads = 8 waves.
// Producers (w 0-3, strip w): swapped QK^T -> keys lane-local softmax
// (2 shfl reduces), defer-rescale, P/sc/flag -> dbuf LDS, lgkmcnt(0),
// raw s_barrier.  Producers run ONE CHUNK AHEAD: softmax(j+1) overlaps
// consumers' PV(j).  Consumers (w 4-7, 64 unique channels): after barrier
// issue V(j+1) reg-prefetch (consumed next chunk -> latency amortized),
// flag-gated rescale, 8 ds_read_b128 P-frags, 32 PV mfma with setprio.
// NO vmcnt drain anywhere in the loop (raw barriers only).
// Epilogue: direct coalesced float4 stores (4 lanes cover each 64B line).
// ---------------------------------------------------------------------------
#define P_OFF   0        // 2 bufs x 4 strips x 16 q x 128B = 16384
#define SC_OFF  16384    // 2 x 64 f32 = 512
#define FL_OFF  16896    // 2 x 16B = 32
#define LL_OFF  16928    // 64 f32 = 256
#define SMEMSZ  17184

__global__ __launch_bounds__(512, 1) void attn_kernel(
    const u16* __restrict__ q, const u16* __restrict__ k, const u16* __restrict__ v,
    const float* __restrict__ input, const float* __restrict__ gamma,
    float* __restrict__ out)
{
    __shared__ __align__(16) char smem[SMEMSZ];
    const int t = threadIdx.x;
    const int w = t >> 6;
    const int lane = t & 63;
    const int g8 = lane >> 4;
    const int l16 = lane & 15;

    const int bid = blockIdx.x;
    const int b = (bid >> 1) & 3;
    const int tile = ((bid >> 3) << 1) | (bid & 1);
    const int i0 = tile * QT;

    const u16* kb = k + (size_t)b * NPOS * CQK;
    const u16* vb = v + (size_t)b * CH * NPOS;

    if (w < 4) {
        // ===================== producer =====================
        const int strip = w;
        const u16* qb = q + (size_t)b * NPOS * CQK;
        bf16x8 qf = *(const bf16x8*)(qb + (size_t)(i0 + strip * 16 + l16) * CQK + g8 * 8);
        float mrun = -__builtin_inff(), lrun = 0.f;

        bf16x8 kA[4], kB[4];
        #pragma unroll
        for (int nt = 0; nt < 4; ++nt)
            kA[nt] = *(const bf16x8*)(kb + (size_t)(nt * 16 + l16) * CQK + g8 * 8);

        // compute chunk c (uses kcur), prefetch K_{c+1} into knxt, publish P[c&1]
        auto pbody = [&](int c, bf16x8 (&kcur)[4], bf16x8 (&knxt)[4]) {
            f32x4 z = {0.f, 0.f, 0.f, 0.f};
            f32x4 s[4];
            #pragma unroll
            for (int nt = 0; nt < 4; ++nt)   // S[key nt*16+g8*4+r][query l16]
                s[nt] = __builtin_amdgcn_mfma_f32_16x16x32_bf16(kcur[nt], qf, z, 0, 0, 0);
            if (c + 1 < NCHK) {
                int j0n = (c + 1) * KT;
                #pragma unroll
                for (int nt = 0; nt < 4; ++nt)
                    knxt[nt] = *(const bf16x8*)(kb + (size_t)(j0n + nt * 16 + l16) * CQK + g8 * 8);
            }
            float mx = s[0][0];
            #pragma unroll
            for (int nt = 0; nt < 4; ++nt)
                #pragma unroll
                for (int r = 0; r < 4; ++r) mx = fmaxf(mx, s[nt][r]);
            mx = fmaxf(mx, __shfl_xor(mx, 16));
            mx = fmaxf(mx, __shfl_xor(mx, 32));
            bool need = mx > mrun + 8.0f;                 // defer-rescale THR=8
            float sc = need ? __expf(mrun - mx) : 1.0f;   // exp(-inf)=0 first time
            if (need) mrun = mx;
            float p[4][4]; float ls = 0.f;
            #pragma unroll
            for (int nt = 0; nt < 4; ++nt)
                #pragma unroll
                for (int r = 0; r < 4; ++r) {
                    p[nt][r] = __expf(s[nt][r] - mrun);
                    ls += p[nt][r];
                }
            ls += __shfl_xor(ls, 16);
            ls += __shfl_xor(ls, 32);
            lrun = lrun * sc + ls;
            const int buf = c & 1;
            char* pb = smem + P_OFF + buf * 8192 + strip * 2048 + l16 * 128;
            int swz = (l16 & 7) << 4;
            #pragma unroll
            for (int nt = 0; nt < 4; ++nt)
                *(uint2*)(pb + ((nt * 32 + g8 * 8) ^ swz)) =
                    make_uint2(pack2(p[nt][0], p[nt][1]), pack2(p[nt][2], p[nt][3]));
            if (g8 == 0)
                *(float*)(smem + SC_OFF + buf * 256 + (strip * 16 + l16) * 4) = sc;
            bool wany = __any(need);
            if (lane == 0)
                *(u32*)(smem + FL_OFF + buf * 16 + strip * 4) = wany ? 1u : 0u;
            asm volatile("s_waitcnt lgkmcnt(0)" ::: "memory");
        };

        pbody(0, kA, kB);                        // chunk 0 before first barrier
        for (int jc = 0; jc < NCHK; jc += 2) {
            __builtin_amdgcn_s_barrier();        // publish P[jc]
            asm volatile("" ::: "memory");
            pbody(jc + 1, kB, kA);               // overlap with consumers' PV(jc)
            __builtin_amdgcn_s_barrier();        // publish P[jc+1]
            asm volatile("" ::: "memory");
            if (jc + 2 < NCHK) pbody(jc + 2, kA, kB);
        }
        if (g8 == 0)
            *(float*)(smem + LL_OFF + (strip * 16 + l16) * 4) = lrun;
        __syncthreads();
    } else {
        // ===================== consumer =====================
        const int ch0 = (w - 4) * 64;
        bf16x8 vA[8], vB[8];
        #pragma unroll
        for (int ct = 0; ct < 4; ++ct)
            #pragma unroll
            for (int ks = 0; ks < 2; ++ks)
                vA[ct * 2 + ks] = *(const bf16x8*)(vb + (size_t)(ch0 + ct * 16 + l16) * NPOS
                                                   + ks * 32 + g8 * 8);
        f32x4 acc[4][4];
        #pragma unroll
        for (int mt = 0; mt < 4; ++mt)
            #pragma unroll
            for (int ct = 0; ct < 4; ++ct)
                acc[mt][ct] = (f32x4){0.f, 0.f, 0.f, 0.f};

        auto cbody = [&](int jc, bf16x8 (&vcur)[8], bf16x8 (&vnxt)[8]) {
            const int buf = jc & 1;
            __builtin_amdgcn_s_barrier();        // P[jc] visible
            asm volatile("" ::: "memory");
            __builtin_amdgcn_sched_barrier(0);
            if (jc + 1 < NCHK) {                 // V(j+1): consumed NEXT chunk
                int j0n = (jc + 1) * KT;
                #pragma unroll
                for (int ct = 0; ct < 4; ++ct)
                    #pragma unroll
                    for (int ks = 0; ks < 2; ++ks)
                        vnxt[ct * 2 + ks] = *(const bf16x8*)(vb + (size_t)(ch0 + ct * 16 + l16) * NPOS
                                                             + j0n + ks * 32 + g8 * 8);
            }
            uint4 fl = *(const uint4*)(smem + FL_OFF + buf * 16);
            if (fl.x | fl.y | fl.z | fl.w) {
                #pragma unroll
                for (int mt = 0; mt < 4; ++mt) {
                    f32x4 ss = *(const f32x4*)(smem + SC_OFF + buf * 256 + (mt * 16 + g8 * 4) * 4);
                    #pragma unroll
                    for (int ct = 0; ct < 4; ++ct) acc[mt][ct] *= ss;
                }
            }
            __builtin_amdgcn_s_setprio(1);
            #pragma unroll
            for (int mt = 0; mt < 4; ++mt) {
                const char* pb = smem + P_OFF + buf * 8192 + mt * 2048 + l16 * 128;
                int swz = (l16 & 7) << 4;
                bf16x8 pa0 = *(const bf16x8*)(pb + ((g8 * 16) ^ swz));
                bf16x8 pa1 = *(const bf16x8*)(pb + ((64 + g8 * 16) ^ swz));
                #pragma unroll
                for (int ct = 0; ct < 4; ++ct) {
                    acc[mt][ct] = __builtin_amdgcn_mfma_f32_16x16x32_bf16(pa0, vcur[ct * 2 + 0], acc[mt][ct], 0, 0, 0);
                    acc[mt][ct] = __builtin_amdgcn_mfma_f32_16x16x32_bf16(pa1, vcur[ct * 2 + 1], acc[mt][ct], 0, 0, 0);
                }
            }
            __builtin_amdgcn_s_setprio(0);
        };

        for (int jc = 0; jc < NCHK; jc += 2) {
            cbody(jc, vA, vB);
            cbody(jc + 1, vB, vA);
        }
        __syncthreads();                          // LL ready

        f32x4 linv[4];
        #pragma unroll
        for (int mt = 0; mt < 4; ++mt) {
            f32x4 lv = *(const f32x4*)(smem + LL_OFF + (mt * 16 + g8 * 4) * 4);
            f32x4 one = {1.f, 1.f, 1.f, 1.f};
            linv[mt] = one / lv;
        }
        const float gmm = gamma[0];
        const float* inb = input + (size_t)b * CH * NPOS;
        float* ob = out + (size_t)b * CH * NPOS;

        #pragma unroll
        for (int mt = 0; mt < 4; ++mt) {
            #pragma unroll
            for (int ct = 0; ct < 4; ++ct) {
                f32x4 val = acc[mt][ct] * linv[mt];
                int ch = ch0 + ct * 16 + l16;
                size_t gi = (size_t)ch * NPOS + i0 + mt * 16 + g8 * 4;
                float4 in4 = *(const float4*)(inb + gi);
                float4 r4;
                r4.x = gmm * val[0] + in4.x;
                r4.y = gmm * val[1] + in4.y;
                r4.z = gmm * val[2] + in4.z;
                r4.w = gmm * val[3] + in4.w;
                *(float4*)(ob + gi) = r4;
            }
        }
    }
}

// ---------------------------------------------------------------------------
extern "C" void kernel_launch(void* const* d_in, const int* in_sizes, int n_in,
                              void* d_out, int out_size, void* d_ws, size_t ws_size,
                              hipStream_t stream) {
    const float* input = (const float*)d_in[0];
    const float* wq    = (const float*)d_in[1];
    const float* bq    = (const float*)d_in[2];
    const float* wk    = (const float*)d_in[3];
    const float* bk    = (const float*)d_in[4];
    const float* wv    = (const float*)d_in[5];
    const float* bv    = (const float*)d_in[6];
    const float* gamma = (const float*)d_in[7];
    float* out = (float*)d_out;

    const size_t qk_elems = (size_t)NB * NPOS * CQK;   // 524288
    const size_t v_elems  = (size_t)NB * CH * NPOS;    // 4194304
    const size_t w_elems  = 320 * 256;                 // 81920
    size_t need = (2 * qk_elems + v_elems + w_elems) * sizeof(u16) + 320 * sizeof(float);
    if (ws_size < need) return;

    u16* qw = (u16*)d_ws;
    u16* kw = qw + qk_elems;
    u16* vw = kw + qk_elems;
    u16* wb = vw + v_elems;
    float* bbuf = (float*)(wb + w_elems);

    wcvt_kernel<<<dim3(80), dim3(256), 0, stream>>>(wq, bq, wk, bk, wv, bv, wb, bbuf);
    qkv_proj_kernel<<<dim3(NB * (NPOS / 32)), dim3(256), 0, stream>>>(input, wb, bbuf, qw, kw, vw);
    attn_kernel<<<dim3(NB * (NPOS / QT)), dim3(512), 0, stream>>>(qw, kw, vw, input, gamma, out);
}

// Round 6
// 116.089 us; speedup vs baseline: 2.2912x; 1.0074x over previous
//
#include <hip/hip_runtime.h>

#define NB   4
#define CH   256
#define CQK  32
#define NPOS 4096
#define KT   64
#define NCHK (NPOS / KT)
#define QT   64
#define LOG2E 1.4426950408889634f
#define THR2  10.0f   // defer-rescale threshold in log2 units (P <= 2^10)

typedef __attribute__((ext_vector_type(8))) short bf16x8;
typedef __attribute__((ext_vector_type(4))) float f32x4;
typedef unsigned short u16;
typedef unsigned int   u32;

static __device__ __forceinline__ u16 f2bf(float x) {
    union { float f; u32 u; } c; c.f = x;
    u32 u = c.u + 0x7FFFu + ((c.u >> 16) & 1u);
    return (u16)(u >> 16);
}
static __device__ __forceinline__ u32 pack2(float a, float b) {
    return (u32)f2bf(a) | ((u32)f2bf(b) << 16);
}

// ---------------------------------------------------------------------------
// W concat + bf16 convert: wb[320][256] bf16 (rows: 32 q | 32 k | 256 v),
// bb[320] f32.  grid 80 x 256.
// ---------------------------------------------------------------------------
__global__ __launch_bounds__(256) void wcvt_kernel(
    const float* __restrict__ wq, const float* __restrict__ bq,
    const float* __restrict__ wk, const float* __restrict__ bk,
    const float* __restrict__ wv, const float* __restrict__ bv,
    u16* __restrict__ wb, float* __restrict__ bb)
{
    int idx = blockIdx.x * 256 + threadIdx.x;
    int e0 = idx * 4;
    const float* src; int off;
    if (e0 < 32 * 256)      { src = wq; off = e0; }
    else if (e0 < 64 * 256) { src = wk; off = e0 - 32 * 256; }
    else                    { src = wv; off = e0 - 64 * 256; }
    float4 v4 = *(const float4*)(src + off);
    *(uint2*)(wb + e0) = make_uint2(pack2(v4.x, v4.y), pack2(v4.z, v4.w));
    if (idx < 320) {
        float b = idx < 32 ? bq[idx] : (idx < 64 ? bk[idx - 32] : bv[idx - 64]);
        bb[idx] = b;
    }
}

// ---------------------------------------------------------------------------
// MFMA QKV projection.  grid = NB * (NPOS/32) = 512 blocks, 256 threads.
// Q output pre-scaled by log2e so attention softmax runs in exp2 domain.
// ---------------------------------------------------------------------------
__global__ __launch_bounds__(256, 1) void qkv_proj_kernel(
    const float* __restrict__ x, const u16* __restrict__ wb, const float* __restrict__ bb,
    u16* __restrict__ qo, u16* __restrict__ ko, u16* __restrict__ vo)
{
    __shared__ u16 ldsx[32][264];
    const int t  = threadIdx.x;
    const int b  = blockIdx.x >> 7;
    const int n0 = (blockIdx.x & 127) * 32;
    const float* xb = x + (size_t)b * CH * NPOS;

    #pragma unroll
    for (int it = 0; it < 4; ++it) {
        int idx = it * 256 + t;
        int cp = idx >> 3;
        int n4 = (idx & 7) * 4;
        int c  = cp * 2;
        float4 a = *(const float4*)(xb + (size_t)c * NPOS + n0 + n4);
        float4 d = *(const float4*)(xb + (size_t)(c + 1) * NPOS + n0 + n4);
        #pragma unroll
        for (int i = 0; i < 4; ++i) {
            int n = n4 + i;
            u32 pv = pack2(((const float*)&a)[i], ((const float*)&d)[i]);
            *(u32*)((char*)ldsx + n * 528 + ((c * 2) ^ ((n & 7) << 4))) = pv;
        }
    }
    __syncthreads();

    const int w = t >> 6, lane = t & 63, g8 = lane >> 4, l16 = lane & 15;

    bf16x8 bf[2][8];
    #pragma unroll
    for (int ns = 0; ns < 2; ++ns) {
        int n = ns * 16 + l16;
        const char* rowp = (const char*)ldsx + n * 528;
        int swz = (n & 7) << 4;
        #pragma unroll
        for (int ks = 0; ks < 8; ++ks)
            bf[ns][ks] = *(const bf16x8*)(rowp + ((ks * 64 + g8 * 16) ^ swz));
    }

    u16* qdst = qo + (size_t)b * NPOS * CQK;
    u16* kdst = ko + (size_t)b * NPOS * CQK;
    u16* vdst = vo + (size_t)b * CH * NPOS;

    bf16x8 afA[8], afB[8];
    #pragma unroll
    for (int ks = 0; ks < 8; ++ks)
        afA[ks] = *(const bf16x8*)(wb + (w * 5 * 16 + l16) * 256 + ks * 32 + g8 * 8);

    #pragma unroll
    for (int j = 0; j < 5; ++j) {
        int ot = w * 5 + j;
        bf16x8* afc = (j & 1) ? afB : afA;
        bf16x8* afn = (j & 1) ? afA : afB;
        if (j + 1 < 5) {
            int otn = ot + 1;
            #pragma unroll
            for (int ks = 0; ks < 8; ++ks)
                afn[ks] = *(const bf16x8*)(wb + (otn * 16 + l16) * 256 + ks * 32 + g8 * 8);
        }
        f32x4 acc[2];
        acc[0] = (f32x4){0.f, 0.f, 0.f, 0.f};
        acc[1] = (f32x4){0.f, 0.f, 0.f, 0.f};
        #pragma unroll
        for (int ks = 0; ks < 8; ++ks) {
            acc[0] = __builtin_amdgcn_mfma_f32_16x16x32_bf16(afc[ks], bf[0][ks], acc[0], 0, 0, 0);
            acc[1] = __builtin_amdgcn_mfma_f32_16x16x32_bf16(afc[ks], bf[1][ks], acc[1], 0, 0, 0);
        }
        float4 bias = *(const float4*)(bb + ot * 16 + g8 * 4);

        if (ot < 4) {
            u16* dst = (ot < 2 ? qdst : kdst);
            float scl = (ot < 2) ? LOG2E : 1.0f;   // Q pre-scaled for exp2 softmax
            int ob = (ot & 1) * 16 + g8 * 4;
            #pragma unroll
            for (int ns = 0; ns < 2; ++ns) {
                int n = n0 + ns * 16 + l16;
                u32 lo = pack2((acc[ns][0] + bias.x) * scl, (acc[ns][1] + bias.y) * scl);
                u32 hi = pack2((acc[ns][2] + bias.z) * scl, (acc[ns][3] + bias.w) * scl);
                *(uint2*)(dst + (size_t)n * CQK + ob) = make_uint2(lo, hi);
            }
        } else {
            int orow = (ot - 4) * 16 + g8 * 4;
            const float* bp = (const float*)&bias;
            #pragma unroll
            for (int r = 0; r < 4; ++r)
                #pragma unroll
                for (int ns = 0; ns < 2; ++ns)
                    vdst[(size_t)(orow + r) * NPOS + n0 + ns * 16 + l16] =
                        f2bf(acc[ns][r] + bp[r]);
        }
    }
}

// ---------------------------------------------------------------------------
// Producer/consumer flash attention.  grid 256, 512 threads = 8 waves.
// R6: shfl-free softmax common path (per-lane max + __any defer check,
// per-lane l partials reduced once at epilogue), exp2-domain softmax
// (Q pre-scaled), consumer hoists P ds_reads ahead of rescale branch.
// ---------------------------------------------------------------------------
#define P_OFF   0        // 2 bufs x 4 strips x 16 q x 128B = 16384
#define SC_OFF  16384    // 2 x 64 f32 = 512
#define FL_OFF  16896    // 2 x 16B = 32
#define LL_OFF  16928    // 64 f32 = 256
#define SMEMSZ  17184

__global__ __launch_bounds__(512, 1) void attn_kernel(
    const u16* __restrict__ q, const u16* __restrict__ k, const u16* __restrict__ v,
    const float* __restrict__ input, const float* __restrict__ gamma,
    float* __restrict__ out)
{
    __shared__ __align__(16) char smem[SMEMSZ];
    const int t = threadIdx.x;
    const int w = t >> 6;
    const int lane = t & 63;
    const int g8 = lane >> 4;
    const int l16 = lane & 15;

    const int bid = blockIdx.x;
    const int b = (bid >> 1) & 3;
    const int tile = ((bid >> 3) << 1) | (bid & 1);
    const int i0 = tile * QT;

    const u16* kb = k + (size_t)b * NPOS * CQK;
    const u16* vb = v + (size_t)b * CH * NPOS;

    if (w < 4) {
        // ===================== producer =====================
        const int strip = w;
        const u16* qb = q + (size_t)b * NPOS * CQK;
        bf16x8 qf = *(const bf16x8*)(qb + (size_t)(i0 + strip * 16 + l16) * CQK + g8 * 8);
        float mrun = -__builtin_inff(), lrun = 0.f;   // lrun is PER-LANE partial

        bf16x8 kA[4], kB[4];
        #pragma unroll
        for (int nt = 0; nt < 4; ++nt)
            kA[nt] = *(const bf16x8*)(kb + (size_t)(nt * 16 + l16) * CQK + g8 * 8);

        auto pbody = [&](int c, bf16x8 (&kcur)[4], bf16x8 (&knxt)[4]) {
            f32x4 z = {0.f, 0.f, 0.f, 0.f};
            f32x4 s[4];
            #pragma unroll
            for (int nt = 0; nt < 4; ++nt)   // S[key nt*16+g8*4+r][query l16]
                s[nt] = __builtin_amdgcn_mfma_f32_16x16x32_bf16(kcur[nt], qf, z, 0, 0, 0);
            if (c + 1 < NCHK) {
                int j0n = (c + 1) * KT;
                #pragma unroll
                for (int nt = 0; nt < 4; ++nt)
                    knxt[nt] = *(const bf16x8*)(kb + (size_t)(j0n + nt * 16 + l16) * CQK + g8 * 8);
            }
            // local max over this lane's 16 keys (no cross-lane in common path)
            float lmax = s[0][0];
            #pragma unroll
            for (int nt = 0; nt < 4; ++nt)
                #pragma unroll
                for (int r = 0; r < 4; ++r) lmax = fmaxf(lmax, s[nt][r]);
            const int buf = c & 1;
            u32 flagval = 0u;
            if (__any(lmax > mrun + THR2)) {          // rare slow path
                float mx = fmaxf(lmax, __shfl_xor(lmax, 16));
                mx = fmaxf(mx, __shfl_xor(mx, 32));   // row max across g8
                mx = fmaxf(mx, mrun);
                float sc = exp2f(mrun - mx);          // exp2(-inf)=0 first time
                mrun = mx;
                lrun *= sc;
                if (g8 == 0)
                    *(float*)(smem + SC_OFF + buf * 256 + (strip * 16 + l16) * 4) = sc;
                flagval = 1u;
            }
            float p[4][4]; float ls = 0.f;
            #pragma unroll
            for (int nt = 0; nt < 4; ++nt)
                #pragma unroll
                for (int r = 0; r < 4; ++r) {
                    p[nt][r] = exp2f(s[nt][r] - mrun);
                    ls += p[nt][r];
                }
            lrun += ls;                               // per-lane partial only
            char* pb = smem + P_OFF + buf * 8192 + strip * 2048 + l16 * 128;
            int swz = (l16 & 7) << 4;
            #pragma unroll
            for (int nt = 0; nt < 4; ++nt)
                *(uint2*)(pb + ((nt * 32 + g8 * 8) ^ swz)) =
                    make_uint2(pack2(p[nt][0], p[nt][1]), pack2(p[nt][2], p[nt][3]));
            if (lane == 0)
                *(u32*)(smem + FL_OFF + buf * 16 + strip * 4) = flagval;
            asm volatile("s_waitcnt lgkmcnt(0)" ::: "memory");
        };

        pbody(0, kA, kB);                        // chunk 0 before first barrier
        for (int jc = 0; jc < NCHK; jc += 2) {
            __builtin_amdgcn_s_barrier();        // publish P[jc]
            asm volatile("" ::: "memory");
            pbody(jc + 1, kB, kA);               // overlaps consumers' PV(jc)
            __builtin_amdgcn_s_barrier();        // publish P[jc+1]
            asm volatile("" ::: "memory");
            if (jc + 2 < NCHK) pbody(jc + 2, kA, kB);
        }
        // epilogue: reduce per-lane l partials across g8 groups ONCE
        lrun += __shfl_xor(lrun, 16);
        lrun += __shfl_xor(lrun, 32);
        if (g8 == 0)
            *(float*)(smem + LL_OFF + (strip * 16 + l16) * 4) = lrun;
        __syncthreads();
    } else {
        // ===================== consumer =====================
        const int ch0 = (w - 4) * 64;
        bf16x8 vA[8], vB[8];
        #pragma unroll
        for (int ct = 0; ct < 4; ++ct)
            #pragma unroll
            for (int ks = 0; ks < 2; ++ks)
                vA[ct * 2 + ks] = *(const bf16x8*)(vb + (size_t)(ch0 + ct * 16 + l16) * NPOS
                                                   + ks * 32 + g8 * 8);
        f32x4 acc[4][4];
        #pragma unroll
        for (int mt = 0; mt < 4; ++mt)
            #pragma unroll
            for (int ct = 0; ct < 4; ++ct)
                acc[mt][ct] = (f32x4){0.f, 0.f, 0.f, 0.f};

        auto cbody = [&](int jc, bf16x8 (&vcur)[8], bf16x8 (&vnxt)[8]) {
            const int buf = jc & 1;
            __builtin_amdgcn_s_barrier();        // P[jc] visible
            asm volatile("" ::: "memory");
            __builtin_amdgcn_sched_barrier(0);
            if (jc + 1 < NCHK) {                 // V(j+1): consumed NEXT chunk
                int j0n = (jc + 1) * KT;
                #pragma unroll
                for (int ct = 0; ct < 4; ++ct)
                    #pragma unroll
                    for (int ks = 0; ks < 2; ++ks)
                        vnxt[ct * 2 + ks] = *(const bf16x8*)(vb + (size_t)(ch0 + ct * 16 + l16) * NPOS
                                                             + j0n + ks * 32 + g8 * 8);
            }
            // hoist flag + ALL P-frag ds_reads before the rescale branch
            uint4 fl = *(const uint4*)(smem + FL_OFF + buf * 16);
            bf16x8 pa[4][2];
            int swz = (l16 & 7) << 4;
            #pragma unroll
            for (int mt = 0; mt < 4; ++mt) {
                const char* pb = smem + P_OFF + buf * 8192 + mt * 2048 + l16 * 128;
                pa[mt][0] = *(const bf16x8*)(pb + ((g8 * 16) ^ swz));
                pa[mt][1] = *(const bf16x8*)(pb + ((64 + g8 * 16) ^ swz));
            }
            if (fl.x | fl.y | fl.z | fl.w) {
                #pragma unroll
                for (int mt = 0; mt < 4; ++mt) {
                    f32x4 ss = *(const f32x4*)(smem + SC_OFF + buf * 256 + (mt * 16 + g8 * 4) * 4);
                    #pragma unroll
                    for (int ct = 0; ct < 4; ++ct) acc[mt][ct] *= ss;
                }
            }
            __builtin_amdgcn_s_setprio(1);
            #pragma unroll
            for (int mt = 0; mt < 4; ++mt) {
                #pragma unroll
                for (int ct = 0; ct < 4; ++ct) {
                    acc[mt][ct] = __builtin_amdgcn_mfma_f32_16x16x32_bf16(pa[mt][0], vcur[ct * 2 + 0], acc[mt][ct], 0, 0, 0);
                    acc[mt][ct] = __builtin_amdgcn_mfma_f32_16x16x32_bf16(pa[mt][1], vcur[ct * 2 + 1], acc[mt][ct], 0, 0, 0);
                }
            }
            __builtin_amdgcn_s_setprio(0);
        };

        for (int jc = 0; jc < NCHK; jc += 2) {
            cbody(jc, vA, vB);
            cbody(jc + 1, vB, vA);
        }
        __syncthreads();                          // LL ready

        f32x4 linv[4];
        #pragma unroll
        for (int mt = 0; mt < 4; ++mt) {
            f32x4 lv = *(const f32x4*)(smem + LL_OFF + (mt * 16 + g8 * 4) * 4);
            f32x4 one = {1.f, 1.f, 1.f, 1.f};
            linv[mt] = one / lv;
        }
        const float gmm = gamma[0];
        const float* inb = input + (size_t)b * CH * NPOS;
        float* ob = out + (size_t)b * CH * NPOS;

        #pragma unroll
        for (int mt = 0; mt < 4; ++mt) {
            #pragma unroll
            for (int ct = 0; ct < 4; ++ct) {
                f32x4 val = acc[mt][ct] * linv[mt];
                int ch = ch0 + ct * 16 + l16;
                size_t gi = (size_t)ch * NPOS + i0 + mt * 16 + g8 * 4;
                float4 in4 = *(const float4*)(inb + gi);
                float4 r4;
                r4.x = gmm * val[0] + in4.x;
                r4.y = gmm * val[1] + in4.y;
                r4.z = gmm * val[2] + in4.z;
                r4.w = gmm * val[3] + in4.w;
                *(float4*)(ob + gi) = r4;
            }
        }
    }
}

// ---------------------------------------------------------------------------
extern "C" void kernel_launch(void* const* d_in, const int* in_sizes, int n_in,
                              void* d_out, int out_size, void* d_ws, size_t ws_size,
                              hipStream_t stream) {
    const float* input = (const float*)d_in[0];
    const float* wq    = (const float*)d_in[1];
    const float* bq    = (const float*)d_in[2];
    const float* wk    = (const float*)d_in[3];
    const float* bk    = (const float*)d_in[4];
    const float* wv    = (const float*)d_in[5];
    const float* bv    = (const float*)d_in[6];
    const float* gamma = (const float*)d_in[7];
    float* out = (float*)d_out;

    const size_t qk_elems = (size_t)NB * NPOS * CQK;   // 524288
    const size_t v_elems  = (size_t)NB * CH * NPOS;    // 4194304
    const size_t w_elems  = 320 * 256;                 // 81920
    size_t need = (2 * qk_elems + v_elems + w_elems) * sizeof(u16) + 320 * sizeof(float);
    if (ws_size < need) return;

    u16* qw = (u16*)d_ws;
    u16* kw = qw + qk_elems;
    u16* vw = kw + qk_elems;
    u16* wb = vw + v_elems;
    float* bbuf = (float*)(wb + w_elems);

    wcvt_kernel<<<dim3(80), dim3(256), 0, stream>>>(wq, bq, wk, bk, wv, bv, wb, bbuf);
    qkv_proj_kernel<<<dim3(NB * (NPOS / 32)), dim3(256), 0, stream>>>(input, wb, bbuf, qw, kw, vw);
    attn_kernel<<<dim3(NB * (NPOS / QT)), dim3(512), 0, stream>>>(qw, kw, vw, input, gamma, out);
}

// Round 7
// 102.709 us; speedup vs baseline: 2.5897x; 1.1303x over previous
//
#include <hip/hip_runtime.h>

#define NB   4
#define CH   256
#define CQK  32
#define NPOS 4096
#define KT   128
#define NCHK (NPOS / KT)     // 32
#define QT   64
#define LOG2E 1.4426950408889634f
#define THR2  10.0f   // defer-rescale threshold in log2 units (P <= 2^10)

typedef __attribute__((ext_vector_type(8))) short bf16x8;
typedef __attribute__((ext_vector_type(4))) float f32x4;
typedef unsigned short u16;
typedef unsigned int   u32;

static __device__ __forceinline__ u16 f2bf(float x) {
    union { float f; u32 u; } c; c.f = x;
    u32 u = c.u + 0x7FFFu + ((c.u >> 16) & 1u);
    return (u16)(u >> 16);
}
static __device__ __forceinline__ u32 pack2(float a, float b) {
    return (u32)f2bf(a) | ((u32)f2bf(b) << 16);
}
static __device__ __forceinline__ u32 cvtpk(float a, float b) {
    u32 r;
    asm("v_cvt_pk_bf16_f32 %0, %1, %2" : "=v"(r) : "v"(a), "v"(b));
    return r;
}
static __device__ __forceinline__ float exp2raw(float x) {
    float r;
    asm("v_exp_f32 %0, %1" : "=v"(r) : "v"(x));
    return r;
}

// ---------------------------------------------------------------------------
// W concat + bf16 convert: wb[320][256] bf16 (rows: 32 q | 32 k | 256 v),
// bb[320] f32.  grid 80 x 256.
// ---------------------------------------------------------------------------
__global__ __launch_bounds__(256) void wcvt_kernel(
    const float* __restrict__ wq, const float* __restrict__ bq,
    const float* __restrict__ wk, const float* __restrict__ bk,
    const float* __restrict__ wv, const float* __restrict__ bv,
    u16* __restrict__ wb, float* __restrict__ bb)
{
    int idx = blockIdx.x * 256 + threadIdx.x;
    int e0 = idx * 4;
    const float* src; int off;
    if (e0 < 32 * 256)      { src = wq; off = e0; }
    else if (e0 < 64 * 256) { src = wk; off = e0 - 32 * 256; }
    else                    { src = wv; off = e0 - 64 * 256; }
    float4 v4 = *(const float4*)(src + off);
    *(uint2*)(wb + e0) = make_uint2(pack2(v4.x, v4.y), pack2(v4.z, v4.w));
    if (idx < 320) {
        float b = idx < 32 ? bq[idx] : (idx < 64 ? bk[idx - 32] : bv[idx - 64]);
        bb[idx] = b;
    }
}

// ---------------------------------------------------------------------------
// MFMA QKV projection.  grid = NB * (NPOS/32) = 512 blocks, 256 threads.
// Q output pre-scaled by log2e so attention softmax runs in exp2 domain.
// ---------------------------------------------------------------------------
__global__ __launch_bounds__(256, 1) void qkv_proj_kernel(
    const float* __restrict__ x, const u16* __restrict__ wb, const float* __restrict__ bb,
    u16* __restrict__ qo, u16* __restrict__ ko, u16* __restrict__ vo)
{
    __shared__ u16 ldsx[32][264];
    const int t  = threadIdx.x;
    const int b  = blockIdx.x >> 7;
    const int n0 = (blockIdx.x & 127) * 32;
    const float* xb = x + (size_t)b * CH * NPOS;

    #pragma unroll
    for (int it = 0; it < 4; ++it) {
        int idx = it * 256 + t;
        int cp = idx >> 3;
        int n4 = (idx & 7) * 4;
        int c  = cp * 2;
        float4 a = *(const float4*)(xb + (size_t)c * NPOS + n0 + n4);
        float4 d = *(const float4*)(xb + (size_t)(c + 1) * NPOS + n0 + n4);
        #pragma unroll
        for (int i = 0; i < 4; ++i) {
            int n = n4 + i;
            u32 pv = pack2(((const float*)&a)[i], ((const float*)&d)[i]);
            *(u32*)((char*)ldsx + n * 528 + ((c * 2) ^ ((n & 7) << 4))) = pv;
        }
    }
    __syncthreads();

    const int w = t >> 6, lane = t & 63, g8 = lane >> 4, l16 = lane & 15;

    bf16x8 bf[2][8];
    #pragma unroll
    for (int ns = 0; ns < 2; ++ns) {
        int n = ns * 16 + l16;
        const char* rowp = (const char*)ldsx + n * 528;
        int swz = (n & 7) << 4;
        #pragma unroll
        for (int ks = 0; ks < 8; ++ks)
            bf[ns][ks] = *(const bf16x8*)(rowp + ((ks * 64 + g8 * 16) ^ swz));
    }

    u16* qdst = qo + (size_t)b * NPOS * CQK;
    u16* kdst = ko + (size_t)b * NPOS * CQK;
    u16* vdst = vo + (size_t)b * CH * NPOS;

    bf16x8 afA[8], afB[8];
    #pragma unroll
    for (int ks = 0; ks < 8; ++ks)
        afA[ks] = *(const bf16x8*)(wb + (w * 5 * 16 + l16) * 256 + ks * 32 + g8 * 8);

    #pragma unroll
    for (int j = 0; j < 5; ++j) {
        int ot = w * 5 + j;
        bf16x8* afc = (j & 1) ? afB : afA;
        bf16x8* afn = (j & 1) ? afA : afB;
        if (j + 1 < 5) {
            int otn = ot + 1;
            #pragma unroll
            for (int ks = 0; ks < 8; ++ks)
                afn[ks] = *(const bf16x8*)(wb + (otn * 16 + l16) * 256 + ks * 32 + g8 * 8);
        }
        f32x4 acc[2];
        acc[0] = (f32x4){0.f, 0.f, 0.f, 0.f};
        acc[1] = (f32x4){0.f, 0.f, 0.f, 0.f};
        #pragma unroll
        for (int ks = 0; ks < 8; ++ks) {
            acc[0] = __builtin_amdgcn_mfma_f32_16x16x32_bf16(afc[ks], bf[0][ks], acc[0], 0, 0, 0);
            acc[1] = __builtin_amdgcn_mfma_f32_16x16x32_bf16(afc[ks], bf[1][ks], acc[1], 0, 0, 0);
        }
        float4 bias = *(const float4*)(bb + ot * 16 + g8 * 4);

        if (ot < 4) {
            u16* dst = (ot < 2 ? qdst : kdst);
            float scl = (ot < 2) ? LOG2E : 1.0f;   // Q pre-scaled for exp2 softmax
            int ob = (ot & 1) * 16 + g8 * 4;
            #pragma unroll
            for (int ns = 0; ns < 2; ++ns) {
                int n = n0 + ns * 16 + l16;
                u32 lo = pack2((acc[ns][0] + bias.x) * scl, (acc[ns][1] + bias.y) * scl);
                u32 hi = pack2((acc[ns][2] + bias.z) * scl, (acc[ns][3] + bias.w) * scl);
                *(uint2*)(dst + (size_t)n * CQK + ob) = make_uint2(lo, hi);
            }
        } else {
            int orow = (ot - 4) * 16 + g8 * 4;
            const float* bp = (const float*)&bias;
            #pragma unroll
            for (int r = 0; r < 4; ++r)
                #pragma unroll
                for (int ns = 0; ns < 2; ++ns)
                    vdst[(size_t)(orow + r) * NPOS + n0 + ns * 16 + l16] =
                        f2bf(acc[ns][r] + bp[r]);
        }
    }
}

// ---------------------------------------------------------------------------
// Producer/consumer flash attention, KT=128 (32 windows).  grid 256,
// 512 threads.  Producers (w 0-3, strip w): 8 QK^T mfma (swapped: keys
// lane-local), in-place K reload, shfl-free softmax fast path, v_exp_f32 /
// v_cvt_pk_bf16_f32, P -> XOR-swizzled dbuf LDS, SC written EVERY window
// (fixes stale-sc bug).  Consumers (w 4-7, 64 unique ch): P frags via 16
// ds_read_b128, 64 PV mfma with setprio; V quarter reloaded in place right
// after its MFMAs (in flight across >= 3/4 of the block + barrier).
// One raw s_barrier per window, no vmcnt drain in the loop.
// ---------------------------------------------------------------------------
#define P_OFF   0        // 2 bufs x 4 strips x 16 q x 256B = 32768
#define SC_OFF  32768    // 2 x 64 f32 = 512
#define FL_OFF  33280    // 2 x 16B = 32
#define LL_OFF  33312    // 64 f32 = 256
#define SMEMSZ  33568

__global__ __launch_bounds__(512, 1) void attn_kernel(
    const u16* __restrict__ q, const u16* __restrict__ k, const u16* __restrict__ v,
    const float* __restrict__ input, const float* __restrict__ gamma,
    float* __restrict__ out)
{
    __shared__ __align__(16) char smem[SMEMSZ];
    const int t = threadIdx.x;
    const int w = t >> 6;
    const int lane = t & 63;
    const int g8 = lane >> 4;
    const int l16 = lane & 15;

    const int bid = blockIdx.x;
    const int b = (bid >> 1) & 3;
    const int tile = ((bid >> 3) << 1) | (bid & 1);
    const int i0 = tile * QT;

    const u16* kb = k + (size_t)b * NPOS * CQK;
    const u16* vb = v + (size_t)b * CH * NPOS;

    if (w < 4) {
        // ===================== producer =====================
        const int strip = w;
        const u16* qb = q + (size_t)b * NPOS * CQK;
        bf16x8 qf = *(const bf16x8*)(qb + (size_t)(i0 + strip * 16 + l16) * CQK + g8 * 8);
        float mrun = -__builtin_inff(), lrun = 0.f;   // lrun is PER-LANE partial

        bf16x8 kc[8];
        #pragma unroll
        for (int nt = 0; nt < 8; ++nt)
            kc[nt] = *(const bf16x8*)(kb + (size_t)(nt * 16 + l16) * CQK + g8 * 8);

        auto pbody = [&](int c) {
            f32x4 z = {0.f, 0.f, 0.f, 0.f};
            f32x4 s[8];
            #pragma unroll
            for (int nt = 0; nt < 8; ++nt)   // S[key nt*16+g8*4+r][query l16]
                s[nt] = __builtin_amdgcn_mfma_f32_16x16x32_bf16(kc[nt], qf, z, 0, 0, 0);
            // in-place K reload for next window (WAR after MFMA issue)
            {
                int j0n = ((c + 1) & (NCHK - 1)) * KT;
                #pragma unroll
                for (int nt = 0; nt < 8; ++nt)
                    kc[nt] = *(const bf16x8*)(kb + (size_t)(j0n + nt * 16 + l16) * CQK + g8 * 8);
            }
            // tree max over this lane's 32 keys
            float m01, m23, mx4[8];
            #pragma unroll
            for (int nt = 0; nt < 8; ++nt)
                mx4[nt] = fmaxf(fmaxf(s[nt][0], s[nt][1]), fmaxf(s[nt][2], s[nt][3]));
            m01 = fmaxf(fmaxf(mx4[0], mx4[1]), fmaxf(mx4[2], mx4[3]));
            m23 = fmaxf(fmaxf(mx4[4], mx4[5]), fmaxf(mx4[6], mx4[7]));
            float lmax = fmaxf(m01, m23);

            const int buf = c & 1;
            float sc = 1.0f;
            u32 flagval = 0u;
            if (__any(lmax > mrun + THR2)) {          // rare slow path
                float mxx = fmaxf(lmax, __shfl_xor(lmax, 16));
                mxx = fmaxf(mxx, __shfl_xor(mxx, 32));
                mxx = fmaxf(mxx, mrun);
                sc = exp2raw(mrun - mxx);             // exp2(-inf)=0 first time
                mrun = mxx;
                lrun *= sc;
                flagval = 1u;
            }
            // SC written EVERY window (sc==1.0 on fast path) — stale-sc fix
            if (g8 == 0)
                *(float*)(smem + SC_OFF + buf * 256 + (strip * 16 + l16) * 4) = sc;

            float p[8][4];
            float ls0 = 0.f, ls1 = 0.f;
            #pragma unroll
            for (int nt = 0; nt < 8; ++nt) {
                float a0 = exp2raw(s[nt][0] - mrun);
                float a1 = exp2raw(s[nt][1] - mrun);
                float a2 = exp2raw(s[nt][2] - mrun);
                float a3 = exp2raw(s[nt][3] - mrun);
                p[nt][0] = a0; p[nt][1] = a1; p[nt][2] = a2; p[nt][3] = a3;
                if (nt & 1) ls1 += (a0 + a1) + (a2 + a3);
                else        ls0 += (a0 + a1) + (a2 + a3);
            }
            lrun += ls0 + ls1;                        // per-lane partial only

            char* pb = smem + P_OFF + buf * 16384 + strip * 4096 + l16 * 256;
            int swz = (l16 & 7) << 4;
            #pragma unroll
            for (int nt = 0; nt < 8; ++nt) {
                u32 r0 = cvtpk(p[nt][0], p[nt][1]);
                u32 r1 = cvtpk(p[nt][2], p[nt][3]);
                *(uint2*)(pb + ((nt * 32 + g8 * 8) ^ swz)) = make_uint2(r0, r1);
            }
            if (lane == 0)
                *(u32*)(smem + FL_OFF + buf * 16 + strip * 4) = flagval;
            asm volatile("s_waitcnt lgkmcnt(0)" ::: "memory");
        };

        pbody(0);                                // window 0 before first barrier
        for (int jc = 0; jc < NCHK; jc += 2) {
            __builtin_amdgcn_s_barrier();        // publish P[jc]
            asm volatile("" ::: "memory");
            pbody(jc + 1);                       // overlaps consumers' PV(jc)
            __builtin_amdgcn_s_barrier();        // publish P[jc+1]
            asm volatile("" ::: "memory");
            if (jc + 2 < NCHK) pbody(jc + 2);
        }
        // epilogue: reduce per-lane l partials across g8 groups ONCE
        lrun += __shfl_xor(lrun, 16);
        lrun += __shfl_xor(lrun, 32);
        if (g8 == 0)
            *(float*)(smem + LL_OFF + (strip * 16 + l16) * 4) = lrun;
        __syncthreads();
    } else {
        // ===================== consumer =====================
        const int ch0 = (w - 4) * 64;
        bf16x8 vc[16];
        #pragma unroll
        for (int ct = 0; ct < 4; ++ct)
            #pragma unroll
            for (int ks = 0; ks < 4; ++ks)
                vc[ct * 4 + ks] = *(const bf16x8*)(vb + (size_t)(ch0 + ct * 16 + l16) * NPOS
                                                   + ks * 32 + g8 * 8);
        f32x4 acc[4][4];
        #pragma unroll
        for (int mt = 0; mt < 4; ++mt)
            #pragma unroll
            for (int ct = 0; ct < 4; ++ct)
                acc[mt][ct] = (f32x4){0.f, 0.f, 0.f, 0.f};

        auto cbody = [&](int jc) {
            const int buf = jc & 1;
            __builtin_amdgcn_s_barrier();        // P[jc] visible
            asm volatile("" ::: "memory");
            __builtin_amdgcn_sched_barrier(0);
            // flag + ALL P-frag ds_reads first
            uint4 fl = *(const uint4*)(smem + FL_OFF + buf * 16);
            bf16x8 pa[4][4];
            int swz = (l16 & 7) << 4;
            #pragma unroll
            for (int mt = 0; mt < 4; ++mt) {
                const char* pb = smem + P_OFF + buf * 16384 + mt * 4096 + l16 * 256;
                #pragma unroll
                for (int ks = 0; ks < 4; ++ks)
                    pa[mt][ks] = *(const bf16x8*)(pb + ((ks * 64 + g8 * 16) ^ swz));
            }
            if (fl.x | fl.y | fl.z | fl.w) {
                #pragma unroll
                for (int mt = 0; mt < 4; ++mt) {
                    f32x4 ss = *(const f32x4*)(smem + SC_OFF + buf * 256 + (mt * 16 + g8 * 4) * 4);
                    #pragma unroll
                    for (int ct = 0; ct < 4; ++ct) acc[mt][ct] *= ss;
                }
            }
            const int j0n = ((jc + 1) & (NCHK - 1)) * KT;
            __builtin_amdgcn_s_setprio(1);
            #pragma unroll
            for (int ct = 0; ct < 4; ++ct) {
                #pragma unroll
                for (int mt = 0; mt < 4; ++mt)
                    #pragma unroll
                    for (int ks = 0; ks < 4; ++ks)
                        acc[mt][ct] = __builtin_amdgcn_mfma_f32_16x16x32_bf16(
                            pa[mt][ks], vc[ct * 4 + ks], acc[mt][ct], 0, 0, 0);
                // vc[ct] dead -> reload in place for next window (in flight
                // across the remaining MFMAs + barrier + P-reads)
                #pragma unroll
                for (int ks = 0; ks < 4; ++ks)
                    vc[ct * 4 + ks] = *(const bf16x8*)(vb + (size_t)(ch0 + ct * 16 + l16) * NPOS
                                                       + j0n + ks * 32 + g8 * 8);
            }
            __builtin_amdgcn_s_setprio(0);
        };

        for (int jc = 0; jc < NCHK; ++jc) cbody(jc);
        __syncthreads();                          // LL ready

        f32x4 linv[4];
        #pragma unroll
        for (int mt = 0; mt < 4; ++mt) {
            f32x4 lv = *(const f32x4*)(smem + LL_OFF + (mt * 16 + g8 * 4) * 4);
            f32x4 one = {1.f, 1.f, 1.f, 1.f};
            linv[mt] = one / lv;
        }
        const float gmm = gamma[0];
        const float* inb = input + (size_t)b * CH * NPOS;
        float* ob = out + (size_t)b * CH * NPOS;

        #pragma unroll
        for (int mt = 0; mt < 4; ++mt) {
            #pragma unroll
            for (int ct = 0; ct < 4; ++ct) {
                f32x4 val = acc[mt][ct] * linv[mt];
                int ch = ch0 + ct * 16 + l16;
                size_t gi = (size_t)ch * NPOS + i0 + mt * 16 + g8 * 4;
                float4 in4 = *(const float4*)(inb + gi);
                float4 r4;
                r4.x = gmm * val[0] + in4.x;
                r4.y = gmm * val[1] + in4.y;
                r4.z = gmm * val[2] + in4.z;
                r4.w = gmm * val[3] + in4.w;
                *(float4*)(ob + gi) = r4;
            }
        }
    }
}

// ---------------------------------------------------------------------------
extern "C" void kernel_launch(void* const* d_in, const int* in_sizes, int n_in,
                              void* d_out, int out_size, void* d_ws, size_t ws_size,
                              hipStream_t stream) {
    const float* input = (const float*)d_in[0];
    const float* wq    = (const float*)d_in[1];
    const float* bq    = (const float*)d_in[2];
    const float* wk    = (const float*)d_in[3];
    const float* bk    = (const float*)d_in[4];
    const float* wv    = (const float*)d_in[5];
    const float* bv    = (const float*)d_in[6];
    const float* gamma = (const float*)d_in[7];
    float* out = (float*)d_out;

    const size_t qk_elems = (size_t)NB * NPOS * CQK;   // 524288
    const size_t v_elems  = (size_t)NB * CH * NPOS;    // 4194304
    const size_t w_elems  = 320 * 256;                 // 81920
    size_t need = (2 * qk_elems + v_elems + w_elems) * sizeof(u16) + 320 * sizeof(float);
    if (ws_size < need) return;

    u16* qw = (u16*)d_ws;
    u16* kw = qw + qk_elems;
    u16* vw = kw + qk_elems;
    u16* wb = vw + v_elems;
    float* bbuf = (float*)(wb + w_elems);

    wcvt_kernel<<<dim3(80), dim3(256), 0, stream>>>(wq, bq, wk, bk, wv, bv, wb, bbuf);
    qkv_proj_kernel<<<dim3(NB * (NPOS / 32)), dim3(256), 0, stream>>>(input, wb, bbuf, qw, kw, vw);
    attn_kernel<<<dim3(NB * (NPOS / QT)), dim3(512), 0, stream>>>(qw, kw, vw, input, gamma, out);
}